// Round 1
// baseline (3994.777 us; speedup 1.0000x reference)
//
#include <hip/hip_runtime.h>

// Batched time-varying LQR: Riccati backward pass + forward rollout.
// T=64, B=128, NS=64 (state), NC=32 (control), NSC=96.
// One workgroup per batch element b; V (symmetric) lives in LDS across the
// 64 sequential timesteps. Forward pass reads K,k (as S columns) from d_ws.

constexpr int T_   = 64;
constexpr int B_   = 128;
constexpr int NS_  = 64;
constexpr int NC_  = 32;
constexpr int NSC_ = 96;

// LDS layout (floats), total 30048 floats = 120,192 B (<160 KiB/CU)
//  Vs  [64][68]   @0      (V, symmetric, padded stride 68)
//  Fs  [64][96]   @4352   (F tile; reused as Bs[64][68] in phase F)
//  Ws  [64][100]  @10496  (W = V F)
//  Qs  [96][100]  @16896  (Q; reused as F^T in forward pass)
//  Ss  [32][68]   @26496  (S = Quu^{-1} [Qux | qu])
//  LT  [32][33]   @28672  (Cholesky factor, transposed: LT[k][i] = L[i][k])
//  invd[32]       @29728
//  qv  [96]       @29760  (q; reused as tau in forward)
//  hv  [64]       @29856  (h = v + V f)
//  vv  [64]       @29920  (v)
//  fv  [64]       @29984  (f)

__global__ __launch_bounds__(256) void lqr_all(
    const float* __restrict__ Cg, const float* __restrict__ cg,
    const float* __restrict__ Fg, const float* __restrict__ fg,
    const float* __restrict__ x0g, float* __restrict__ outg,
    float* __restrict__ Sws)
{
  const int b   = blockIdx.x;
  const int tid = threadIdx.x;

  __shared__ float smem[30048];
  float (*Vs)[68]   = (float(*)[68]) (smem + 0);
  float (*Fs)[96]   = (float(*)[96]) (smem + 4352);
  float (*Bs)[68]   = (float(*)[68]) (smem + 4352);   // aliases Fs (F dead by then)
  float (*Ws)[100]  = (float(*)[100])(smem + 10496);
  float (*Qs)[100]  = (float(*)[100])(smem + 16896);
  float (*Ss)[68]   = (float(*)[68]) (smem + 26496);
  float (*LT)[33]   = (float(*)[33]) (smem + 28672);
  float* invd = smem + 29728;
  float* qv   = smem + 29760;
  float* hv   = smem + 29856;
  float* vv   = smem + 29920;
  float* fv   = smem + 29984;

  // init V = 0, v = 0
  for (int e = tid; e < 4352; e += 256) smem[e] = 0.f;
  if (tid < NS_) vv[tid] = 0.f;
  __syncthreads();

  // ================= backward Riccati pass =================
  for (int t = T_ - 1; t >= 0; --t) {
    const size_t tb = (size_t)t * B_ + b;
    const float* Ct = Cg + tb * (NSC_ * NSC_);
    const float* ct = cg + tb * NSC_;
    const float* Ft = Fg + tb * (NS_ * NSC_);
    const float* ft = fg + tb * NS_;

    // ---- phase A: load F (64x96), c (96), f (64)
    {
      const float4* F4 = (const float4*)Ft;
#pragma unroll
      for (int k = 0; k < 6; ++k) {
        int e4 = tid + k * 256;            // 0..1535 (1536 float4 = 6144 floats)
        float4 val = F4[e4];
        int r = e4 / 24, c4 = (e4 % 24) * 4;
        *(float4*)&Fs[r][c4] = val;
      }
      if (tid < NSC_) qv[tid] = ct[tid];
      if (tid >= 128 && tid < 192) fv[tid - 128] = ft[tid - 128];
    }
    __syncthreads();

    // ---- phase B: h = v + V f (tid<64);  W = V F (all threads, 4x6 tiles)
    if (tid < NS_) {
      float acc = vv[tid];
#pragma unroll 8
      for (int u = 0; u < NS_; ++u) acc += Vs[u][tid] * fv[u];  // V symmetric
      hv[tid] = acc;
    }
    {
      const int s0 = (tid >> 4) * 4;       // 0..60
      const int j0 = (tid & 15) * 6;       // 0..90
      float acc[4][6];
#pragma unroll
      for (int a = 0; a < 4; ++a)
#pragma unroll
        for (int j = 0; j < 6; ++j) acc[a][j] = 0.f;
#pragma unroll 4
      for (int u = 0; u < NS_; ++u) {
        float av[4], bv[6];
#pragma unroll
        for (int a = 0; a < 4; ++a) av[a] = Vs[u][s0 + a];  // row read (V sym)
#pragma unroll
        for (int j = 0; j < 6; ++j) bv[j] = Fs[u][j0 + j];
#pragma unroll
        for (int a = 0; a < 4; ++a)
#pragma unroll
          for (int j = 0; j < 6; ++j) acc[a][j] += av[a] * bv[j];
      }
#pragma unroll
      for (int a = 0; a < 4; ++a)
#pragma unroll
        for (int j = 0; j < 6; ++j) Ws[s0 + a][j0 + j] = acc[a][j];
    }
    __syncthreads();

    // ---- phase C: Q = C + F^T W (6x6 tiles, C prefetched to regs);  q += F^T h
    {
      const int i0 = (tid >> 4) * 6;
      const int j0 = (tid & 15) * 6;
      float creg[6][6];
#pragma unroll
      for (int a = 0; a < 6; ++a) {
        const float* p = Ct + (i0 + a) * NSC_ + j0;
#pragma unroll
        for (int j = 0; j < 6; ++j) creg[a][j] = p[j];   // hidden under GEMM below
      }
      float acc[6][6];
#pragma unroll
      for (int a = 0; a < 6; ++a)
#pragma unroll
        for (int j = 0; j < 6; ++j) acc[a][j] = 0.f;
#pragma unroll 4
      for (int s = 0; s < NS_; ++s) {
        float av[6], bv[6];
#pragma unroll
        for (int a = 0; a < 6; ++a) av[a] = Fs[s][i0 + a];
#pragma unroll
        for (int j = 0; j < 6; ++j) bv[j] = Ws[s][j0 + j];
#pragma unroll
        for (int a = 0; a < 6; ++a)
#pragma unroll
          for (int j = 0; j < 6; ++j) acc[a][j] += av[a] * bv[j];
      }
#pragma unroll
      for (int a = 0; a < 6; ++a)
#pragma unroll
        for (int j = 0; j < 6; ++j) Qs[i0 + a][j0 + j] = acc[a][j] + creg[a][j];
    }
    if (tid < NSC_) {
      float acc = qv[tid];
#pragma unroll 8
      for (int s = 0; s < NS_; ++s) acc += Fs[s][tid] * hv[s];
      qv[tid] = acc;
    }
    __syncthreads();

    // ---- phase D: Cholesky of Quu = L L^T (one wave, lanes 0..31)
    if (tid < 32) {
      const int i = tid;
      for (int j = 0; j < 32; ++j) {
        float dot = 0.f;
        for (int k = 0; k < j; ++k) dot += LT[k][i] * LT[k][j];
        float dj  = __shfl(dot, j);
        float d   = Qs[64 + j][64 + j] - dj;
        float rin = 1.0f / sqrtf(d);
        if (i == j) invd[j] = rin;
        if (i >= j) {
          float val = (i == j) ? d * rin : (Qs[64 + i][64 + j] - dot) * rin;
          LT[j][i] = val;
        }
      }
    }
    __syncthreads();

    // ---- phase E: S = Quu^{-1} [Qux | qu], one thread per RHS column (65)
    if (tid < 65) {
      float xr[32];
#pragma unroll
      for (int i = 0; i < 32; ++i) {
        float v = (tid < 64) ? Qs[64 + i][tid] : qv[64 + i];
#pragma unroll
        for (int k = 0; k < i; ++k) v -= LT[k][i] * xr[k];   // L[i][k] broadcast
        xr[i] = v * invd[i];
      }
#pragma unroll
      for (int i = 31; i >= 0; --i) {
        float v = xr[i];
#pragma unroll
        for (int k = i + 1; k < 32; ++k) v -= LT[i][k] * xr[k];  // L^T
        xr[i] = v * invd[i];
      }
      float* Sg = Sws + tb * (NC_ * 65);
#pragma unroll
      for (int i = 0; i < 32; ++i) {
        Ss[i][tid]       = xr[i];
        Sg[i * 65 + tid] = xr[i];
      }
    }
    __syncthreads();

    // ---- phase F1: Bmat = Qxu * S[:, :64] (4x4 tiles);  vn = q - Qxu S[:,64]
    {
      const int i0 = (tid >> 4) * 4;
      const int j0 = (tid & 15) * 4;
      float acc[4][4];
#pragma unroll
      for (int a = 0; a < 4; ++a)
#pragma unroll
        for (int j = 0; j < 4; ++j) acc[a][j] = 0.f;
#pragma unroll 4
      for (int m = 0; m < 32; ++m) {
        float qa[4], sb[4];
#pragma unroll
        for (int a = 0; a < 4; ++a) qa[a] = Qs[i0 + a][64 + m];
#pragma unroll
        for (int j = 0; j < 4; ++j) sb[j] = Ss[m][j0 + j];
#pragma unroll
        for (int a = 0; a < 4; ++a)
#pragma unroll
          for (int j = 0; j < 4; ++j) acc[a][j] += qa[a] * sb[j];
      }
#pragma unroll
      for (int a = 0; a < 4; ++a)
#pragma unroll
        for (int j = 0; j < 4; ++j) Bs[i0 + a][j0 + j] = acc[a][j];
    }
    if (tid < NS_) {
      float acc = qv[tid];
#pragma unroll 4
      for (int m = 0; m < 32; ++m) acc -= Qs[tid][64 + m] * Ss[m][64];
      vv[tid] = acc;   // vn = qx + Qxu k  (k = -S[:,64])
    }
    __syncthreads();

    // ---- phase F2: V = sym(Qxx - Bmat)
    {
      const int i0 = (tid >> 4) * 4;
      const int j0 = (tid & 15) * 4;
#pragma unroll
      for (int a = 0; a < 4; ++a)
#pragma unroll
        for (int j = 0; j < 4; ++j)
          Vs[i0 + a][j0 + j] = Qs[i0 + a][j0 + j]
                             - 0.5f * (Bs[i0 + a][j0 + j] + Bs[j0 + j][i0 + a]);
    }
    __syncthreads();
  }

  // ================= forward rollout =================
  float (*FsT)[100] = Qs;   // F^T staged here (96 rows x 64 cols used)
  float* tau = qv;          // tau[0:64]=x, tau[64:96]=u
  if (tid < NS_) tau[tid] = x0g[(size_t)b * NS_ + tid];
  __syncthreads();

  for (int t = 0; t < T_; ++t) {
    const size_t tb = (size_t)t * B_ + b;
    const float* Ft = Fg + tb * (NS_ * NSC_);
    const float* ft = fg + tb * NS_;
    const float* Sg = Sws + tb * (NC_ * 65);

    for (int e = tid; e < NC_ * 65; e += 256) Ss[e / 65][e % 65] = Sg[e];
    {
      const float4* F4 = (const float4*)Ft;
#pragma unroll
      for (int k = 0; k < 6; ++k) {
        int e4 = tid + k * 256;
        float4 val = F4[e4];
        int r = e4 / 24, c0 = (e4 % 24) * 4;
        FsT[c0 + 0][r] = val.x; FsT[c0 + 1][r] = val.y;
        FsT[c0 + 2][r] = val.z; FsT[c0 + 3][r] = val.w;
      }
    }
    if (tid >= 64 && tid < 128) fv[tid - 64] = ft[tid - 64];
    __syncthreads();

    // u = K x + k = -(S[:, :64] x + S[:, 64])
    if (tid < NC_) {
      float acc = Ss[tid][64];
#pragma unroll 8
      for (int i = 0; i < NS_; ++i) acc += Ss[tid][i] * tau[i];
      tau[64 + tid] = -acc;
    }
    __syncthreads();

    // emit tau; x_next = F tau + f
    if (tid < NSC_) outg[tb * NSC_ + tid] = tau[tid];
    float xn = 0.f;
    if (tid < NS_) {
      xn = fv[tid];
#pragma unroll 8
      for (int i = 0; i < NSC_; ++i) xn += FsT[i][tid] * tau[i];
    }
    __syncthreads();
    if (tid < NS_) tau[tid] = xn;
    __syncthreads();
  }
}

extern "C" void kernel_launch(void* const* d_in, const int* in_sizes, int n_in,
                              void* d_out, int out_size, void* d_ws, size_t ws_size,
                              hipStream_t stream) {
  const float* C  = (const float*)d_in[0];
  const float* c  = (const float*)d_in[1];
  const float* F  = (const float*)d_in[2];
  const float* f  = (const float*)d_in[3];
  const float* x0 = (const float*)d_in[4];
  float* out = (float*)d_out;
  float* S   = (float*)d_ws;   // needs T*B*32*65*4 = 68.2 MB

  lqr_all<<<dim3(B_), dim3(256), 0, stream>>>(C, c, F, f, x0, out, S);
}